// Round 1
// baseline (38.211 us; speedup 1.0000x reference)
//
#include <hip/hip_runtime.h>
#include <math.h>

#define M_ROWS 8192
#define N_COLS 4096
#define BLOCK 256

__global__ __launch_bounds__(BLOCK) void row_lse_kernel(const float* __restrict__ x,
                                                        float* __restrict__ lse) {
    const int m = blockIdx.x;
    const int t = threadIdx.x;
    const float* row = x + (size_t)m * N_COLS;

    // Load 16 elements per thread (4x float4, stride-256 across block => coalesced 16B/lane)
    float4 v[4];
#pragma unroll
    for (int k = 0; k < 4; ++k) {
        v[k] = reinterpret_cast<const float4*>(row)[t + k * BLOCK];
    }

    // Pass 1: sum of squares + row max (dist is monotone-decreasing in x)
    float ssq = 0.f;
    float xmax = -INFINITY;
#pragma unroll
    for (int k = 0; k < 4; ++k) {
        ssq += v[k].x * v[k].x + v[k].y * v[k].y + v[k].z * v[k].z + v[k].w * v[k].w;
        xmax = fmaxf(xmax, fmaxf(fmaxf(v[k].x, v[k].y), fmaxf(v[k].z, v[k].w)));
    }

    // Wave (64-lane) reduction
#pragma unroll
    for (int off = 32; off > 0; off >>= 1) {
        ssq += __shfl_xor(ssq, off);
        xmax = fmaxf(xmax, __shfl_xor(xmax, off));
    }
    __shared__ float s_ssq[4], s_max[4];
    const int wave = t >> 6;
    if ((t & 63) == 0) { s_ssq[wave] = ssq; s_max[wave] = xmax; }
    __syncthreads();
    ssq  = s_ssq[0] + s_ssq[1] + s_ssq[2] + s_ssq[3];
    xmax = fmaxf(fmaxf(s_max[0], s_max[1]), fmaxf(s_max[2], s_max[3]));

    // min dist over the row; logsumexp shift is -mindist
    const float mindist = sqrtf(fmaxf(ssq - 2.f * xmax + 1.f, 0.f));

    // Pass 2 (from registers): sum exp(mindist - dist_i)
    float esum = 0.f;
#pragma unroll
    for (int k = 0; k < 4; ++k) {
        const float e0 = v[k].x, e1 = v[k].y, e2 = v[k].z, e3 = v[k].w;
        esum += __expf(mindist - sqrtf(fmaxf(ssq - 2.f * e0 + 1.f, 0.f)));
        esum += __expf(mindist - sqrtf(fmaxf(ssq - 2.f * e1 + 1.f, 0.f)));
        esum += __expf(mindist - sqrtf(fmaxf(ssq - 2.f * e2 + 1.f, 0.f)));
        esum += __expf(mindist - sqrtf(fmaxf(ssq - 2.f * e3 + 1.f, 0.f)));
    }
#pragma unroll
    for (int off = 32; off > 0; off >>= 1) esum += __shfl_xor(esum, off);
    __shared__ float s_es[4];
    if ((t & 63) == 0) s_es[wave] = esum;
    __syncthreads();
    if (t == 0) {
        const float total = s_es[0] + s_es[1] + s_es[2] + s_es[3];
        lse[m] = -mindist + __logf(total);
    }
}

__global__ __launch_bounds__(BLOCK) void mean_kernel(const float* __restrict__ lse,
                                                     float* __restrict__ out) {
    const int t = threadIdx.x;
    float s = 0.f;
    for (int i = t; i < M_ROWS; i += BLOCK) s += lse[i];
#pragma unroll
    for (int off = 32; off > 0; off >>= 1) s += __shfl_xor(s, off);
    __shared__ float sw[4];
    if ((t & 63) == 0) sw[t >> 6] = s;
    __syncthreads();
    if (t == 0) out[0] = (sw[0] + sw[1] + sw[2] + sw[3]) * (1.0f / (float)M_ROWS);
}

extern "C" void kernel_launch(void* const* d_in, const int* in_sizes, int n_in,
                              void* d_out, int out_size, void* d_ws, size_t ws_size,
                              hipStream_t stream) {
    const float* x = (const float*)d_in[0];
    float* out = (float*)d_out;
    float* lse = (float*)d_ws;  // 8192 floats = 32 KB scratch

    row_lse_kernel<<<M_ROWS, BLOCK, 0, stream>>>(x, lse);
    mean_kernel<<<1, BLOCK, 0, stream>>>(lse, out);
}